// Round 1
// baseline (716.924 us; speedup 1.0000x reference)
//
#include <hip/hip_runtime.h>
#include <math.h>

#define B_ 32
#define INLEN 10
#define LIN_ 16384
#define NPOLY 12
#define MM 6
#define CH 20
#define NB 4
#define RECEPT 25
#define L0 16434      // length after first conv
#define TTILE 252     // outputs per tile (multiple of 6)
#define NW 43         // TTILE/6 + 1 windows
#define XS_LEN 264    // TTILE + 12 halo
#define GS_LEN 254    // TTILE + 2
#define GS_STRIDE 256

__device__ __forceinline__ float gelu_exact(float x) {
    return 0.5f * x * (1.0f + erff(x * 0.70710678118654752440f));
}

// ---------------- first conv: (B,10,16384) wrap-padded -> (B,20,16434) ----------------
__global__ void k_first(const float* __restrict__ in, const float* __restrict__ wf,
                        float* __restrict__ out) {
    int t = blockIdx.x * blockDim.x + threadIdx.x;
    int b = blockIdx.y;
    if (t >= L0) return;
    const float* inb = in + (size_t)b * INLEN * LIN_;
    float xw[INLEN][3];
#pragma unroll
    for (int ci = 0; ci < INLEN; ++ci) {
#pragma unroll
        for (int k = 0; k < 3; ++k) {
            int idx = t + k - RECEPT;
            idx = (idx < 0) ? idx + LIN_ : (idx >= LIN_ ? idx - LIN_ : idx);
            xw[ci][k] = inb[ci * LIN_ + idx];
        }
    }
    float* outb = out + (size_t)b * CH * L0;
#pragma unroll
    for (int co = 0; co < CH; ++co) {
        float acc = 0.f;
#pragma unroll
        for (int ci = 0; ci < INLEN; ++ci)
#pragma unroll
            for (int k = 0; k < 3; ++k)
                acc = fmaf(xw[ci][k], wf[(co * INLEN + ci) * 3 + k], acc);
        outb[(size_t)co * L0 + t] = acc;
    }
}

// ---------------- fused block: residual conv path + Legendre multiwavelet path ----------------
__global__ __launch_bounds__(256, 2)
void k_block(const float* __restrict__ x, float* __restrict__ xn,
             const float* __restrict__ wA, const float* __restrict__ wB,
             const float* __restrict__ linm, const float* __restrict__ fd,
             const float* __restrict__ fr, int l) {
    const int lout = l - 12;
    const int tid  = threadIdx.x;
    const int t0   = blockIdx.x * TTILE;       // multiple of 6
    const int b    = blockIdx.y;

    __shared__ float xs[CH][XS_LEN];           // x tile
    __shared__ float gs[CH][GS_STRIDE];        // gelu(conv_a(x)) tile
    __shared__ float lxs[NW][CH * MM];         // Legendre coeffs, layout [wl][u], u = m*20+c
    __shared__ float lm_s[CH * MM * MM];       // lin_m[i] : [g][o][i]
    __shared__ float fr_s[MM * NPOLY];         // filt_r (unscaled; net factor is exactly fr)

    const float* xb = x + (size_t)b * CH * l;

    for (int i = tid; i < CH * MM * MM; i += 256) lm_s[i] = linm[i];
    for (int i = tid; i < MM * NPOLY; i += 256)   fr_s[i] = fr[i];

    // stage A: load x tile (zero-fill past end; those outputs are masked)
    for (int i = tid; i < CH * XS_LEN; i += 256) {
        int c = i / XS_LEN, p = i % XS_LEN;
        int gp = t0 + p;
        xs[c][p] = (gp < l) ? xb[(size_t)c * l + gp] : 0.f;
    }
    __syncthreads();

    // stage B: g[p] = gelu(conv_a(x))[global p = t0+4+tid], needs xs[.][tid+4 .. tid+6]
    if (tid < GS_LEN) {
        float xw[CH][3];
#pragma unroll
        for (int ci = 0; ci < CH; ++ci) {
            xw[ci][0] = xs[ci][tid + 4];
            xw[ci][1] = xs[ci][tid + 5];
            xw[ci][2] = xs[ci][tid + 6];
        }
#pragma unroll
        for (int co = 0; co < CH; ++co) {
            float acc = 0.f;
#pragma unroll
            for (int ci = 0; ci < CH; ++ci)
#pragma unroll
                for (int k = 0; k < 3; ++k)
                    acc = fmaf(xw[ci][k], wA[(co * CH + ci) * 3 + k], acc);
            gs[co][tid] = gelu_exact(acc);
        }
    }

    // stage C1: Legendre decomposition per (window, channel): Lx[m] = sum_k x[6wl+k] * fd[m][k]/2
    for (int item = tid; item < NW * CH; item += 256) {
        int wl = item / CH, c = item % CH;
        float xv[NPOLY];
#pragma unroll
        for (int k = 0; k < NPOLY; ++k) xv[k] = xs[c][6 * wl + k];
#pragma unroll
        for (int m = 0; m < MM; ++m) {
            float acc = 0.f;
#pragma unroll
            for (int k = 0; k < NPOLY; ++k)
                acc = fmaf(xv[k], fd[m * NPOLY + k], acc);
            lxs[wl][m * CH + c] = acc * 0.5f;
        }
    }
    __syncthreads();

    // stage C2: grouped mode mixing on flattened mode-major index u = m*20+c,
    // groups are 6-consecutive u's (block-diagonal -> safe in place)
    for (int item = tid; item < NW * CH; item += 256) {
        int wl = item / CH, g = item % CH;
        float iv[MM], ov[MM];
#pragma unroll
        for (int i = 0; i < MM; ++i) iv[i] = lxs[wl][g * MM + i];
#pragma unroll
        for (int o = 0; o < MM; ++o) {
            float acc = 0.f;
#pragma unroll
            for (int i = 0; i < MM; ++i)
                acc = fmaf(iv[i], lm_s[(g * MM + o) * MM + i], acc);
            ov[o] = acc;
        }
#pragma unroll
        for (int o = 0; o < MM; ++o) lxs[wl][g * MM + o] = ov[o];
    }
    __syncthreads();

    // stage D: out[t'] = gelu( rec[t'+6] + conv_b(g)[t'+4] )
    if (tid < TTILE && t0 + tid < lout) {
        const int tp = tid;
        float gw[CH][3];
#pragma unroll
        for (int ci = 0; ci < CH; ++ci) {
            gw[ci][0] = gs[ci][tp];
            gw[ci][1] = gs[ci][tp + 1];
            gw[ci][2] = gs[ci][tp + 2];
        }
        const int r1  = tp % 6;        // (t0+tp+6) % 6
        const int wl1 = tp / 6 + 1;    // local window (t'+6)/6
        float frA[MM], frB[MM];
#pragma unroll
        for (int m = 0; m < MM; ++m) {
            frA[m] = fr_s[m * NPOLY + r1];
            frB[m] = fr_s[m * NPOLY + r1 + 6];
        }
        float* xnb = xn + (size_t)b * CH * lout;
#pragma unroll
        for (int co = 0; co < CH; ++co) {
            float acc = 0.f;
#pragma unroll
            for (int ci = 0; ci < CH; ++ci)
#pragma unroll
                for (int k = 0; k < 3; ++k)
                    acc = fmaf(gw[ci][k], wB[(co * CH + ci) * 3 + k], acc);
            float rec = 0.f;
#pragma unroll
            for (int m = 0; m < MM; ++m) {
                rec = fmaf(lxs[wl1][m * CH + co], frA[m], rec);
                rec = fmaf(lxs[wl1 - 1][m * CH + co], frB[m], rec);
            }
            xnb[(size_t)co * lout + t0 + tp] = gelu_exact(acc + rec);
        }
    }
}

// ---------------- final: gelu(20->128) -> 128->1, slice to 16384 ----------------
__global__ void k_final(const float* __restrict__ x, const float* __restrict__ w11,
                        const float* __restrict__ wout, float* __restrict__ out) {
    int t = blockIdx.x * blockDim.x + threadIdx.x;
    int b = blockIdx.y;
    if (t >= LIN_) return;
    const int l4 = L0 - NB * 12;   // 16386
    const float* xb = x + (size_t)b * CH * l4;
    float xv[CH];
#pragma unroll
    for (int c = 0; c < CH; ++c) xv[c] = xb[(size_t)c * l4 + t];
    float acc = 0.f;
    for (int h = 0; h < 128; ++h) {
        float hv = 0.f;
#pragma unroll
        for (int c = 0; c < CH; ++c)
            hv = fmaf(xv[c], w11[h * CH + c], hv);
        acc = fmaf(gelu_exact(hv), wout[h], acc);
    }
    out[(size_t)b * LIN_ + t] = acc;
}

extern "C" void kernel_launch(void* const* d_in, const int* in_sizes, int n_in,
                              void* d_out, int out_size, void* d_ws, size_t ws_size,
                              hipStream_t stream) {
    const float* input   = (const float*)d_in[0];
    const float* w_first = (const float*)d_in[1];
    const float* conv_a  = (const float*)d_in[2];
    const float* conv_b  = (const float*)d_in[3];
    const float* lin_m   = (const float*)d_in[4];
    const float* w11     = (const float*)d_in[5];
    const float* w_out   = (const float*)d_in[6];
    const float* filt_d  = (const float*)d_in[7];
    const float* filt_r  = (const float*)d_in[8];
    float* out = (float*)d_out;

    const size_t bufElems = (size_t)B_ * CH * L0;   // 10,517,760 floats = 42.07 MB
    float* xA = (float*)d_ws;
    float* xB = xA + bufElems;

    {
        dim3 grid((L0 + 255) / 256, B_);
        k_first<<<grid, 256, 0, stream>>>(input, w_first, xA);
    }

    int l = L0;
    float* cur = xA;
    float* nxt = xB;
    for (int i = 0; i < NB; ++i) {
        int lout  = l - 12;
        int tiles = (lout + TTILE - 1) / TTILE;
        dim3 grid(tiles, B_);
        k_block<<<grid, 256, 0, stream>>>(cur, nxt,
                                          conv_a + i * CH * CH * 3,
                                          conv_b + i * CH * CH * 3,
                                          lin_m + i * CH * MM * MM,
                                          filt_d, filt_r, l);
        float* tswap = cur; cur = nxt; nxt = tswap;
        l = lout;
    }

    {
        dim3 grid((LIN_ + 255) / 256, B_);
        k_final<<<grid, 256, 0, stream>>>(cur, w11, w_out, out);
    }
}